// Round 11
// baseline (300.141 us; speedup 1.0000x reference)
//
#include <hip/hip_runtime.h>
#include <cstdint>
#include <cstddef>

using u16 = unsigned short;
using bf16x8 = __attribute__((ext_vector_type(8))) __bf16;
using f32x4  = __attribute__((ext_vector_type(4))) float;
using f32x16 = __attribute__((ext_vector_type(16))) float;

static __device__ __forceinline__ u16 f2bf(float f) {
  unsigned u = __builtin_bit_cast(unsigned, f);
  unsigned r = (u + 0x7fffu + ((u >> 16) & 1u)) >> 16;  // RNE
  return (u16)r;
}
static __device__ __forceinline__ float bf2f(u16 h) {
  unsigned u = ((unsigned)h) << 16;
  return __builtin_bit_cast(float, u);
}
static __device__ __forceinline__ float eluf(float x) {
  return x > 0.f ? x : expm1f(x);
}
static __device__ __forceinline__ void gload16(const u16* g, u16* l) {
  __builtin_amdgcn_global_load_lds(
      (const __attribute__((address_space(1))) void*)g,
      (__attribute__((address_space(3))) void*)l, 16, 0, 0);
}

// ---------------------------------------------------------------------------
// Merged weight transpose+convert: all 6 matrices in one launch.
// Each block does one 32x32 tile of one (matrix, expert).
// src (E, Ksrc, Nsrc) f32 -> dst bf16 (Nsrc*E, Kpad), row n' = dout*E + e.
// ---------------------------------------------------------------------------
__global__ void transpose_all(const float* __restrict__ s0, u16* __restrict__ d0,
                              const float* __restrict__ s1, u16* __restrict__ d1,
                              const float* __restrict__ s2, u16* __restrict__ d2,
                              const float* __restrict__ s3, u16* __restrict__ d3,
                              const float* __restrict__ s4, u16* __restrict__ d4,
                              const float* __restrict__ s5, u16* __restrict__ d5) {
  // seg: {Ksrc, Nsrc, Kpad, E, nKb, nDb, start}
  // 0 gw0: 272,512,288,1 : 9*16      =144   start 0
  // 1 gw1: 768,512,768,1 : 24*16     =384   start 144
  // 2 w0 : 515,512,576,8 : 18*16*8   =2304  start 528
  // 3 w1 : 768,512,768,8 : 24*16*8   =3072  start 2832
  // 4 w2 : 768,512,768,8 : 3072             start 5904
  // 5 wo : 768,256,768,8 : 24*8*8    =1536  start 8976  (total 10512)
  const int bid = blockIdx.x;
  const float* src; u16* dst;
  int Ksrc, Nsrc, Kpad, nKb, local;
  if (bid < 144)       { src=s0; dst=d0; Ksrc=272; Nsrc=512; Kpad=288; nKb=9;  local=bid; }
  else if (bid < 528)  { src=s1; dst=d1; Ksrc=768; Nsrc=512; Kpad=768; nKb=24; local=bid-144; }
  else if (bid < 2832) { src=s2; dst=d2; Ksrc=515; Nsrc=512; Kpad=576; nKb=18; local=bid-528; }
  else if (bid < 5904) { src=s3; dst=d3; Ksrc=768; Nsrc=512; Kpad=768; nKb=24; local=bid-2832; }
  else if (bid < 8976) { src=s4; dst=d4; Ksrc=768; Nsrc=512; Kpad=768; nKb=24; local=bid-5904; }
  else                 { src=s5; dst=d5; Ksrc=768; Nsrc=256; Kpad=768; nKb=24; local=bid-8976; }
  const int nDb   = Nsrc >> 5;
  const int perE  = nKb * nDb;
  const int e     = local / perE;
  const int rem   = local - e * perE;
  const int k0    = (rem % nKb) * 32;
  const int d0i   = (rem / nKb) * 32;
  const int E     = (bid < 528) ? 1 : 8;

  __shared__ float tile[32][33];
  const int tx = threadIdx.x;  // 0..31
  const int ty = threadIdx.y;  // 0..7
  const float* s = src + (size_t)e * Ksrc * Nsrc;
#pragma unroll
  for (int i = 0; i < 4; ++i) {
    const int k = k0 + ty + i * 8;
    float v = 0.f;
    if (k < Ksrc) v = s[(size_t)k * Nsrc + d0i + tx];
    tile[ty + i * 8][tx] = v;
  }
  __syncthreads();
#pragma unroll
  for (int i = 0; i < 4; ++i) {
    const int d = d0i + ty + i * 8;
    dst[((size_t)d * E + e) * Kpad + k0 + tx] = f2bf(tile[tx][ty + i * 8]);
  }
}

// ---------------------------------------------------------------------------
// Build bf16 concat buffers.
// ---------------------------------------------------------------------------
__global__ void prep_cat(const float* __restrict__ z, const float* __restrict__ p,
                         const float* __restrict__ vh, const float* __restrict__ xc,
                         u16* __restrict__ catP, u16* __restrict__ catE0,
                         u16* __restrict__ cat0, u16* __restrict__ cat1) {
  const int m = blockIdx.x;
  const int t = threadIdx.x;  // 0..255
  const u16 zb = f2bf(z[(size_t)m * 256 + t]);
  catP [(size_t)m * 288 + t] = zb;
  catE0[(size_t)m * 576 + t] = zb;
  cat0 [(size_t)m * 768 + t] = zb;
  cat1 [(size_t)m * 768 + t] = zb;
  if (t < 32) {
    const u16 val = (t < 16) ? f2bf(p[(size_t)m * 16 + t]) : (u16)0;
    catP[(size_t)m * 288 + 256 + t] = val;
  }
  for (int c = 256 + t; c < 576; c += 256) {
    const int idx = c - 256;
    float v = 0.f;
    if (idx < 3)        v = vh[(size_t)m * 3 + idx];
    else if (idx < 259) v = xc[(size_t)m * 256 + (idx - 3)];
    catE0[(size_t)m * 576 + c] = f2bf(v);
  }
}

// ---------------------------------------------------------------------------
// Gating layer 2 (N=8) + softmax: one wave per token.
// ---------------------------------------------------------------------------
__global__ __launch_bounds__(256) void gating_tail(const u16* __restrict__ cat,
                                                   const float* __restrict__ gw2,
                                                   const float* __restrict__ gb2,
                                                   float* __restrict__ ew) {
  const int ln = threadIdx.x & 63;
  const int token = (int)((blockIdx.x * 256 + threadIdx.x) >> 6);
  const u16* row = cat + (size_t)token * 768;
  float a[8] = {0.f, 0.f, 0.f, 0.f, 0.f, 0.f, 0.f, 0.f};
#pragma unroll
  for (int kk = 0; kk < 12; ++kk) {
    const int k = kk * 64 + ln;
    const float x = bf2f(row[k]);
    const float4* wr = reinterpret_cast<const float4*>(gw2 + (size_t)k * 8);
    const float4 w0 = wr[0], w1 = wr[1];
    a[0] += x * w0.x; a[1] += x * w0.y; a[2] += x * w0.z; a[3] += x * w0.w;
    a[4] += x * w1.x; a[5] += x * w1.y; a[6] += x * w1.z; a[7] += x * w1.w;
  }
#pragma unroll
  for (int j = 0; j < 8; ++j) {
#pragma unroll
    for (int d = 32; d > 0; d >>= 1) a[j] += __shfl_xor(a[j], d);
    a[j] += gb2[j];
  }
  float mx = a[0];
#pragma unroll
  for (int j = 1; j < 8; ++j) mx = fmaxf(mx, a[j]);
  float s = 0.f, pj[8];
#pragma unroll
  for (int j = 0; j < 8; ++j) { pj[j] = expf(a[j] - mx); s += pj[j]; }
  const float inv = 1.f / s;
  if (ln == 0) {
#pragma unroll
    for (int j = 0; j < 8; ++j) ew[(size_t)token * 8 + j] = pj[j] * inv;
  }
}

// ---------------------------------------------------------------------------
// 128x128 bf16 MFMA GEMM (gating layer 0, K=288, BK=32). Proven R2 kernel.
// ---------------------------------------------------------------------------
template <int MODE, int BK>
__global__ __launch_bounds__(256) void gemm_mfma(
    const u16* __restrict__ A, const u16* __restrict__ Bt,
    const float* __restrict__ bias, const float* __restrict__ ew,
    void* __restrict__ outp, int M, int N, int K,
    int out_stride, int out_col0) {
  constexpr int SLOTS = BK / 8;
  constexpr int SSH   = (BK == 32) ? 2 : 3;
  constexpr int CROWS = 1024 / (BK * 2);
  constexpr int LOADS = BK / 16;

  __shared__ alignas(16) u16 As[128 * BK];
  __shared__ alignas(16) u16 Bs[128 * BK];

  const int tid = threadIdx.x;
  const int ln  = tid & 63;
  const int wv  = tid >> 6;
  const int wr  = wv >> 1;
  const int wc  = wv & 1;
  const int m0  = blockIdx.y * 128;
  const int n0  = blockIdx.x * 128;

  const int lrow  = ln >> SSH;
  const int lslot = ln & (SLOTS - 1);
  const int fw    = (BK == 64) ? (lrow & 7) : ((lrow >> 1) & 3);
  const int gcol  = ((lslot ^ fw) << 3);
  const int c0    = wv * LOADS;

  const u16* gA[LOADS]; const u16* gB[LOADS];
  u16* lA[LOADS]; u16* lB[LOADS];
#pragma unroll
  for (int t = 0; t < LOADS; ++t) {
    const int rowg = (c0 + t) * CROWS + lrow;
    gA[t] = A  + (size_t)(m0 + rowg) * K + gcol;
    gB[t] = Bt + (size_t)(n0 + rowg) * K + gcol;
    lA[t] = &As[(size_t)(c0 + t) * 512];
    lB[t] = &Bs[(size_t)(c0 + t) * 512];
  }

  f32x4 acc[4][4];
#pragma unroll
  for (int i = 0; i < 4; ++i)
#pragma unroll
    for (int j = 0; j < 4; ++j) acc[i][j] = (f32x4){0.f, 0.f, 0.f, 0.f};

  const int ar  = ln & 15;
  const int hi  = ln >> 4;
  const int arf = (BK == 64) ? (ar & 7) : ((ar >> 1) & 3);

  const int kIters = K / BK;
  for (int kt = 0; kt < kIters; ++kt) {
#pragma unroll
    for (int t = 0; t < LOADS; ++t) gload16(gA[t], lA[t]);
#pragma unroll
    for (int t = 0; t < LOADS; ++t) gload16(gB[t], lB[t]);
#pragma unroll
    for (int t = 0; t < LOADS; ++t) { gA[t] += BK; gB[t] += BK; }
    __syncthreads();

#pragma unroll
    for (int k32 = 0; k32 < BK / 32; ++k32) {
      bf16x8 af[4], bfv[4];
#pragma unroll
      for (int i = 0; i < 4; ++i)
        af[i] = *reinterpret_cast<const bf16x8*>(
            &As[(size_t)(wr * 64 + i * 16 + ar) * BK + (((k32 * 4 + hi) ^ arf) << 3)]);
#pragma unroll
      for (int j = 0; j < 4; ++j)
        bfv[j] = *reinterpret_cast<const bf16x8*>(
            &Bs[(size_t)(wc * 64 + j * 16 + ar) * BK + (((k32 * 4 + hi) ^ arf) << 3)]);
#pragma unroll
      for (int i = 0; i < 4; ++i)
#pragma unroll
        for (int j = 0; j < 4; ++j)
          acc[i][j] = __builtin_amdgcn_mfma_f32_16x16x32_bf16(af[i], bfv[j], acc[i][j], 0, 0, 0);
    }
    __syncthreads();
  }

  const int m0w = m0 + wr * 64 + (ln >> 4) * 4;
  const int n0w = n0 + wc * 64 + (ln & 15);
  u16* outb = (u16*)outp;
#pragma unroll
  for (int j = 0; j < 4; ++j) {
    const int n = n0w + j * 16;
    const float bv = bias[n];
#pragma unroll
    for (int i = 0; i < 4; ++i) {
#pragma unroll
      for (int r = 0; r < 4; ++r) {
        const int m = m0w + i * 16 + r;
        outb[(size_t)m * out_stride + out_col0 + n] = f2bf(eluf(acc[i][j][r] + bv));
      }
    }
  }
}

// ---------------------------------------------------------------------------
// Gating layer 1 GEMM: 64x128 tile (M x N), 4 waves (1M x 4N), BK=64,
// single-buffer 24 KiB. Grid (N/128, M/64) = 512 blocks -> 2 blocks/CU
// co-resident (fixes the old 256-block 1/CU zero-overlap regime).
// Wave wv owns 64 x 32 (cols wc*32..+32). Standard (non-expert) epilogue:
// bf16 out at [m][out_col0+n], +bias[n], elu.
// ---------------------------------------------------------------------------
__global__ __launch_bounds__(256) void gemm_g(
    const u16* __restrict__ A, const u16* __restrict__ Bt,
    const float* __restrict__ bias, void* __restrict__ outp,
    int K, int out_stride, int out_col0) {
  constexpr int BK = 64;
  __shared__ alignas(16) u16 As[64 * BK];    // 8 KiB
  __shared__ alignas(16) u16 Bs[128 * BK];   // 16 KiB

  const int tid = threadIdx.x;
  const int ln  = tid & 63;
  const int wv  = tid >> 6;       // 0..3
  const int wc  = wv;             // N quarter
  const int m0  = blockIdx.y * 64;
  const int n0  = blockIdx.x * 128;

  const int lrow  = ln >> 3;          // 0..7
  const int gslot = (ln & 7) ^ lrow;  // pre-swizzled 16B slot
  // A: 8 chunks of 8 rows; wave wv stages chunks {wv*2, wv*2+1}
  // B: 16 chunks; wave wv stages chunks {wv*4 .. wv*4+3}
  const u16* gA[2]; const u16* gB[4];
#pragma unroll
  for (int q = 0; q < 2; ++q)
    gA[q] = A + (size_t)(m0 + (wv * 2 + q) * 8 + lrow) * K + gslot * 8;
#pragma unroll
  for (int q = 0; q < 4; ++q)
    gB[q] = Bt + (size_t)(n0 + (wv * 4 + q) * 8 + lrow) * K + gslot * 8;

  f32x4 acc[4][2];
#pragma unroll
  for (int i = 0; i < 4; ++i)
#pragma unroll
    for (int j = 0; j < 2; ++j) acc[i][j] = (f32x4){0.f, 0.f, 0.f, 0.f};

  const int ar  = ln & 15;
  const int hi  = ln >> 4;
  const int arf = ar & 7;
  const int sl0 = (hi ^ arf) << 3;
  const int sl1 = ((4 + hi) ^ arf) << 3;

  const int nt = K / BK;
  for (int t = 0; t < nt; ++t) {
#pragma unroll
    for (int q = 0; q < 2; ++q) {
      gload16(gA[q], &As[(size_t)((wv * 2 + q) * 8) * 64]);
      gA[q] += BK;
    }
#pragma unroll
    for (int q = 0; q < 4; ++q) {
      gload16(gB[q], &Bs[(size_t)((wv * 4 + q) * 8) * 64]);
      gB[q] += BK;
    }
    __syncthreads();

#pragma unroll
    for (int kk = 0; kk < 2; ++kk) {
      const int sl = kk ? sl1 : sl0;
      bf16x8 av[4], bv[2];
#pragma unroll
      for (int i = 0; i < 4; ++i)
        av[i] = *reinterpret_cast<const bf16x8*>(&As[(size_t)(i * 16 + ar) * 64 + sl]);
#pragma unroll
      for (int j = 0; j < 2; ++j)
        bv[j] = *reinterpret_cast<const bf16x8*>(
            &Bs[(size_t)(wc * 32 + j * 16 + ar) * 64 + sl]);
      __builtin_amdgcn_s_setprio(1);
#pragma unroll
      for (int i = 0; i < 4; ++i)
#pragma unroll
        for (int j = 0; j < 2; ++j)
          acc[i][j] = __builtin_amdgcn_mfma_f32_16x16x32_bf16(av[i], bv[j], acc[i][j], 0, 0, 0);
      __builtin_amdgcn_s_setprio(0);
    }
    __syncthreads();
  }

  u16* outb = (u16*)outp;
#pragma unroll
  for (int j = 0; j < 2; ++j) {
    const int n = n0 + wc * 32 + j * 16 + (ln & 15);
    const float bv = bias[n];
#pragma unroll
    for (int i = 0; i < 4; ++i) {
#pragma unroll
      for (int r = 0; r < 4; ++r) {
        const int m = m0 + i * 16 + hi * 4 + r;
        outb[(size_t)m * out_stride + out_col0 + n] = f2bf(eluf(acc[i][j][r] + bv));
      }
    }
  }
}

// ---------------------------------------------------------------------------
// Expert GEMM, R10 structure (128x128, 4 waves, BK=64, single-buffer 32 KiB,
// 3 blocks/CU, transposed output) with 32x32x16 MFMA: 16 MFMA + 16 ds_read
// per K-tile (half the MFMA instructions at identical matrix-pipe cycles).
// acc[f_i][f_j] = mfma_32x32x16(bv[f_i], av[f_j], .) = D[n, m]:
//   n = n0 + wc*64 + f_i*32 + (reg&3) + 8*(reg>>2) + 4*(ln>>5)
//   m = m0 + wr*64 + f_j*32 + (ln&31)
// => e = (reg&3) + 4*(ln>>5) (register-local), dout = nb_fi + (reg>>2).
// Expert reduction: 4 reg-local terms + ONE shfl_xor(32).
// Operand layout (A&B): row/col = lane&31, k = (lane>>5)*8 + elem.
// LDS XOR-swizzle unchanged: slot g at (g ^ (row&7)); g = kk*2 + (ln>>5).
// MODE 1: bf16 write + elu. MODE 2: fp32 write, no elu (final layer).
// ---------------------------------------------------------------------------
template <int MODE>
__global__ __launch_bounds__(256, 3) void gemm128e(
    const u16* __restrict__ A, const u16* __restrict__ Bt,
    const float* __restrict__ bias, const float* __restrict__ ew,
    void* __restrict__ outp, int N, int K, int out_stride, int out_col0) {
  constexpr int BK = 64;
  __shared__ alignas(16) u16 As[128 * BK];  // 16 KiB
  __shared__ alignas(16) u16 Bs[128 * BK];  // 16 KiB

  const int tid = threadIdx.x;
  const int ln  = tid & 63;
  const int wv  = tid >> 6;       // 0..3
  const int wr  = wv >> 1;        // M half
  const int wc  = wv & 1;         // N half
  const int m0  = blockIdx.y * 128;
  const int n0  = blockIdx.x * 128;

  // staging (unchanged from R10): wave wv covers rows [wv*32, wv*32+32)
  const int lrow  = ln >> 3;
  const int gslot = (ln & 7) ^ lrow;
  const u16* gA[4]; const u16* gB[4];
#pragma unroll
  for (int q = 0; q < 4; ++q) {
    const int row = wv * 32 + q * 8 + lrow;
    gA[q] = A  + (size_t)(m0 + row) * K + gslot * 8;
    gB[q] = Bt + (size_t)(n0 + row) * K + gslot * 8;
  }

  f32x16 acc[2][2];
#pragma unroll
  for (int i = 0; i < 2; ++i)
#pragma unroll
    for (int j = 0; j < 2; ++j)
#pragma unroll
      for (int r = 0; r < 16; ++r) acc[i][j][r] = 0.f;

  const int ar32 = ln & 31;       // row within 32-block
  const int hi2  = ln >> 5;       // 0..1 (k-group)
  const int arf  = ar32 & 7;      // read-side swizzle

  const int nt = K / BK;

  for (int t = 0; t < nt; ++t) {
#pragma unroll
    for (int q = 0; q < 4; ++q) {
      gload16(gA[q], &As[(size_t)(wv * 32 + q * 8) * 64]);
      gload16(gB[q], &Bs[(size_t)(wv * 32 + q * 8) * 64]);
      gA[q] += BK; gB[q] += BK;
    }
    __syncthreads();  // drains vmcnt(0): tile staged & visible

    const u16* Ab = &As[(size_t)(wr * 64 + ar32) * 64];
    const u16* Bb = &Bs[(size_t)(wc * 64 + ar32) * 64];
    __builtin_amdgcn_s_setprio(1);
#pragma unroll
    for (int kk = 0; kk < 4; ++kk) {
      const int sl = (((kk * 2 + hi2) ^ arf) << 3);  // u16 offset of 16B slot
      bf16x8 bv[2], av[2];
#pragma unroll
      for (int f = 0; f < 2; ++f) {
        bv[f] = *reinterpret_cast<const bf16x8*>(Bb + (size_t)f * 32 * 64 + sl);
        av[f] = *reinterpret_cast<const bf16x8*>(Ab + (size_t)f * 32 * 64 + sl);
      }
#pragma unroll
      for (int i = 0; i < 2; ++i)
#pragma unroll
        for (int j = 0; j < 2; ++j)
          acc[i][j] = __builtin_amdgcn_mfma_f32_32x32x16_bf16(bv[i], av[j], acc[i][j], 0, 0, 0);
    }
    __builtin_amdgcn_s_setprio(0);
    __syncthreads();  // all reads done before next stage overwrites
  }

  // Transposed epilogue (32x32 D layout).
  const int Dout = N >> 3;
  float ewv[2][4];   // [f_j][r] = ew[m(f_j)*8 + r + 4*hi2]
#pragma unroll
  for (int j = 0; j < 2; ++j) {
    const int m = m0 + wr * 64 + j * 32 + ar32;
#pragma unroll
    for (int r = 0; r < 4; ++r) ewv[j][r] = ew[(size_t)m * 8 + r + 4 * hi2];
  }
  float bs[2][4][4]; // [f_i][dq][r] = bias[(r+4*hi2)*Dout + nb_fi + dq]
#pragma unroll
  for (int i = 0; i < 2; ++i) {
    const int nb = (n0 + wc * 64 + i * 32) >> 3;
#pragma unroll
    for (int dq = 0; dq < 4; ++dq)
#pragma unroll
      for (int r = 0; r < 4; ++r)
        bs[i][dq][r] = bias[(size_t)(r + 4 * hi2) * Dout + nb + dq];
  }

#pragma unroll
  for (int i = 0; i < 2; ++i) {
    const int nb = (n0 + wc * 64 + i * 32) >> 3;
#pragma unroll
    for (int j = 0; j < 2; ++j) {
      const int m = m0 + wr * 64 + j * 32 + ar32;
#pragma unroll
      for (int dq = 0; dq < 4; ++dq) {
        float s = 0.f;
#pragma unroll
        for (int r = 0; r < 4; ++r)
          s += (acc[i][j][dq * 4 + r] + bs[i][dq][r]) * ewv[j][r];
        s += __shfl_xor(s, 32);   // combine experts 0-3 with 4-7
        if (hi2 == 0) {
          const int d = nb + dq;
          if (MODE == 1) {
            ((u16*)outp)[(size_t)m * out_stride + out_col0 + d] = f2bf(eluf(s));
          } else {
            ((float*)outp)[(size_t)m * out_stride + d] = s;
          }
        }
      }
    }
  }
}

// ---------------------------------------------------------------------------
extern "C" void kernel_launch(void* const* d_in, const int* in_sizes, int n_in,
                              void* d_out, int out_size, void* d_ws, size_t ws_size,
                              hipStream_t stream) {
  const float* z   = (const float*)d_in[0];
  const float* p   = (const float*)d_in[1];
  const float* vh  = (const float*)d_in[2];
  const float* xc  = (const float*)d_in[3];
  const float* gw0 = (const float*)d_in[4];
  const float* gb0 = (const float*)d_in[5];
  const float* gw1 = (const float*)d_in[6];
  const float* gb1 = (const float*)d_in[7];
  const float* gw2 = (const float*)d_in[8];
  const float* gb2 = (const float*)d_in[9];
  const float* w0  = (const float*)d_in[10];
  const float* b0  = (const float*)d_in[11];
  const float* w1  = (const float*)d_in[12];
  const float* b1  = (const float*)d_in[13];
  const float* w2  = (const float*)d_in[14];
  const float* b2  = (const float*)d_in[15];
  const float* wo  = (const float*)d_in[16];
  const float* bo  = (const float*)d_in[17];
  float* out = (float*)d_out;

  char* ws = (char*)d_ws;
  size_t off = 0;
  auto alloc = [&](size_t bytes) {
    char* pp = ws + off;
    off += (bytes + 255) & ~(size_t)255;
    return pp;
  };
  u16* gw0t  = (u16*)alloc((size_t)512 * 288 * 2);
  u16* gw1t  = (u16*)alloc((size_t)512 * 768 * 2);
  u16* w0t   = (u16*)alloc((size_t)4096 * 576 * 2);
  u16* w1t   = (u16*)alloc((size_t)4096 * 768 * 2);
  u16* w2t   = (u16*)alloc((size_t)4096 * 768 * 2);
  u16* wot   = (u16*)alloc((size_t)2048 * 768 * 2);
  u16* catP  = (u16*)alloc((size_t)8192 * 288 * 2);
  u16* catE0 = (u16*)alloc((size_t)8192 * 576 * 2);
  u16* cat0  = (u16*)alloc((size_t)8192 * 768 * 2);
  u16* cat1  = (u16*)alloc((size_t)8192 * 768 * 2);
  float* ew  = (float*)alloc((size_t)8192 * 8 * 4);
  (void)ws_size; (void)in_sizes; (void)n_in; (void)out_size;

  transpose_all<<<10512, dim3(32, 8), 0, stream>>>(gw0, gw0t, gw1, gw1t,
                                                   w0, w0t, w1, w1t,
                                                   w2, w2t, wo, wot);
  prep_cat<<<8192, 256, 0, stream>>>(z, p, vh, xc, catP, catE0, cat0, cat1);

  // gating
  gemm_mfma<0, 32><<<dim3(4, 64), 256, 0, stream>>>(catP, gw0t, gb0, nullptr, cat0,
                                                    8192, 512, 288, 768, 256);
  gemm_g<<<dim3(4, 128), 256, 0, stream>>>(cat0, gw1t, gb1, cat1, 768, 768, 256);
  gating_tail<<<2048, 256, 0, stream>>>(cat1, gw2, gb2, ew);

  // expert layers: 128^2 BK=64 single-buffer, 3 blocks/CU, 32x32x16 MFMA
  gemm128e<1><<<dim3(32, 64), 256, 0, stream>>>(catE0, w0t, b0, ew, cat0,
                                                4096, 576, 768, 256);
  gemm128e<1><<<dim3(32, 64), 256, 0, stream>>>(cat0, w1t, b1, ew, cat1,
                                                4096, 768, 768, 256);
  gemm128e<1><<<dim3(32, 64), 256, 0, stream>>>(cat1, w2t, b2, ew, cat0,
                                                4096, 768, 768, 256);
  gemm128e<2><<<dim3(16, 64), 256, 0, stream>>>(cat0, wot, bo, ew, out,
                                                2048, 768, 256, 0);
}

// Round 12
// 269.163 us; speedup vs baseline: 1.1151x; 1.1151x over previous
//
#include <hip/hip_runtime.h>
#include <cstdint>
#include <cstddef>

using u16 = unsigned short;
using bf16x8 = __attribute__((ext_vector_type(8))) __bf16;
using f32x4  = __attribute__((ext_vector_type(4))) float;

static __device__ __forceinline__ u16 f2bf(float f) {
  unsigned u = __builtin_bit_cast(unsigned, f);
  unsigned r = (u + 0x7fffu + ((u >> 16) & 1u)) >> 16;  // RNE
  return (u16)r;
}
static __device__ __forceinline__ float bf2f(u16 h) {
  unsigned u = ((unsigned)h) << 16;
  return __builtin_bit_cast(float, u);
}
static __device__ __forceinline__ float eluf(float x) {
  return x > 0.f ? x : expm1f(x);
}
static __device__ __forceinline__ void gload16(const u16* g, u16* l) {
  __builtin_amdgcn_global_load_lds(
      (const __attribute__((address_space(1))) void*)g,
      (__attribute__((address_space(3))) void*)l, 16, 0, 0);
}

// ---------------------------------------------------------------------------
// Merged weight transpose+convert: all 6 matrices in one launch.
// src (E, Ksrc, Nsrc) f32 -> dst bf16 (Nsrc*E, Kpad), row n' = dout*E + e.
// ---------------------------------------------------------------------------
__global__ void transpose_all(const float* __restrict__ s0, u16* __restrict__ d0,
                              const float* __restrict__ s1, u16* __restrict__ d1,
                              const float* __restrict__ s2, u16* __restrict__ d2,
                              const float* __restrict__ s3, u16* __restrict__ d3,
                              const float* __restrict__ s4, u16* __restrict__ d4,
                              const float* __restrict__ s5, u16* __restrict__ d5) {
  const int bid = blockIdx.x;
  const float* src; u16* dst;
  int Ksrc, Nsrc, Kpad, nKb, local;
  if (bid < 144)       { src=s0; dst=d0; Ksrc=272; Nsrc=512; Kpad=288; nKb=9;  local=bid; }
  else if (bid < 528)  { src=s1; dst=d1; Ksrc=768; Nsrc=512; Kpad=768; nKb=24; local=bid-144; }
  else if (bid < 2832) { src=s2; dst=d2; Ksrc=515; Nsrc=512; Kpad=576; nKb=18; local=bid-528; }
  else if (bid < 5904) { src=s3; dst=d3; Ksrc=768; Nsrc=512; Kpad=768; nKb=24; local=bid-2832; }
  else if (bid < 8976) { src=s4; dst=d4; Ksrc=768; Nsrc=512; Kpad=768; nKb=24; local=bid-5904; }
  else                 { src=s5; dst=d5; Ksrc=768; Nsrc=256; Kpad=768; nKb=24; local=bid-8976; }
  const int nDb   = Nsrc >> 5;
  const int perE  = nKb * nDb;
  const int e     = local / perE;
  const int rem   = local - e * perE;
  const int k0    = (rem % nKb) * 32;
  const int d0i   = (rem / nKb) * 32;
  const int E     = (bid < 528) ? 1 : 8;

  __shared__ float tile[32][33];
  const int tx = threadIdx.x;  // 0..31
  const int ty = threadIdx.y;  // 0..7
  const float* s = src + (size_t)e * Ksrc * Nsrc;
#pragma unroll
  for (int i = 0; i < 4; ++i) {
    const int k = k0 + ty + i * 8;
    float v = 0.f;
    if (k < Ksrc) v = s[(size_t)k * Nsrc + d0i + tx];
    tile[ty + i * 8][tx] = v;
  }
  __syncthreads();
#pragma unroll
  for (int i = 0; i < 4; ++i) {
    const int d = d0i + ty + i * 8;
    dst[((size_t)d * E + e) * Kpad + k0 + tx] = f2bf(tile[tx][ty + i * 8]);
  }
}

// ---------------------------------------------------------------------------
// Build bf16 concat buffers.
// ---------------------------------------------------------------------------
__global__ void prep_cat(const float* __restrict__ z, const float* __restrict__ p,
                         const float* __restrict__ vh, const float* __restrict__ xc,
                         u16* __restrict__ catP, u16* __restrict__ catE0,
                         u16* __restrict__ cat0, u16* __restrict__ cat1) {
  const int m = blockIdx.x;
  const int t = threadIdx.x;  // 0..255
  const u16 zb = f2bf(z[(size_t)m * 256 + t]);
  catP [(size_t)m * 288 + t] = zb;
  catE0[(size_t)m * 576 + t] = zb;
  cat0 [(size_t)m * 768 + t] = zb;
  cat1 [(size_t)m * 768 + t] = zb;
  if (t < 32) {
    const u16 val = (t < 16) ? f2bf(p[(size_t)m * 16 + t]) : (u16)0;
    catP[(size_t)m * 288 + 256 + t] = val;
  }
  for (int c = 256 + t; c < 576; c += 256) {
    const int idx = c - 256;
    float v = 0.f;
    if (idx < 3)        v = vh[(size_t)m * 3 + idx];
    else if (idx < 259) v = xc[(size_t)m * 256 + (idx - 3)];
    catE0[(size_t)m * 576 + c] = f2bf(v);
  }
}

// ---------------------------------------------------------------------------
// Gating layer 2 (N=8) + softmax: one wave per token.
// ---------------------------------------------------------------------------
__global__ __launch_bounds__(256) void gating_tail(const u16* __restrict__ cat,
                                                   const float* __restrict__ gw2,
                                                   const float* __restrict__ gb2,
                                                   float* __restrict__ ew) {
  const int ln = threadIdx.x & 63;
  const int token = (int)((blockIdx.x * 256 + threadIdx.x) >> 6);
  const u16* row = cat + (size_t)token * 768;
  float a[8] = {0.f, 0.f, 0.f, 0.f, 0.f, 0.f, 0.f, 0.f};
#pragma unroll
  for (int kk = 0; kk < 12; ++kk) {
    const int k = kk * 64 + ln;
    const float x = bf2f(row[k]);
    const float4* wr = reinterpret_cast<const float4*>(gw2 + (size_t)k * 8);
    const float4 w0 = wr[0], w1 = wr[1];
    a[0] += x * w0.x; a[1] += x * w0.y; a[2] += x * w0.z; a[3] += x * w0.w;
    a[4] += x * w1.x; a[5] += x * w1.y; a[6] += x * w1.z; a[7] += x * w1.w;
  }
#pragma unroll
  for (int j = 0; j < 8; ++j) {
#pragma unroll
    for (int d = 32; d > 0; d >>= 1) a[j] += __shfl_xor(a[j], d);
    a[j] += gb2[j];
  }
  float mx = a[0];
#pragma unroll
  for (int j = 1; j < 8; ++j) mx = fmaxf(mx, a[j]);
  float s = 0.f, pj[8];
#pragma unroll
  for (int j = 0; j < 8; ++j) { pj[j] = expf(a[j] - mx); s += pj[j]; }
  const float inv = 1.f / s;
  if (ln == 0) {
#pragma unroll
    for (int j = 0; j < 8; ++j) ew[(size_t)token * 8 + j] = pj[j] * inv;
  }
}

// ---------------------------------------------------------------------------
// 128x128 bf16 MFMA GEMM (gating layer 0, K=288, BK=32). Proven R2 kernel.
// ---------------------------------------------------------------------------
template <int MODE, int BK>
__global__ __launch_bounds__(256) void gemm_mfma(
    const u16* __restrict__ A, const u16* __restrict__ Bt,
    const float* __restrict__ bias, const float* __restrict__ ew,
    void* __restrict__ outp, int M, int N, int K,
    int out_stride, int out_col0) {
  constexpr int SLOTS = BK / 8;
  constexpr int SSH   = (BK == 32) ? 2 : 3;
  constexpr int CROWS = 1024 / (BK * 2);
  constexpr int LOADS = BK / 16;

  __shared__ alignas(16) u16 As[128 * BK];
  __shared__ alignas(16) u16 Bs[128 * BK];

  const int tid = threadIdx.x;
  const int ln  = tid & 63;
  const int wv  = tid >> 6;
  const int wr  = wv >> 1;
  const int wc  = wv & 1;
  const int m0  = blockIdx.y * 128;
  const int n0  = blockIdx.x * 128;

  const int lrow  = ln >> SSH;
  const int lslot = ln & (SLOTS - 1);
  const int fw    = (BK == 64) ? (lrow & 7) : ((lrow >> 1) & 3);
  const int gcol  = ((lslot ^ fw) << 3);
  const int c0    = wv * LOADS;

  const u16* gA[LOADS]; const u16* gB[LOADS];
  u16* lA[LOADS]; u16* lB[LOADS];
#pragma unroll
  for (int t = 0; t < LOADS; ++t) {
    const int rowg = (c0 + t) * CROWS + lrow;
    gA[t] = A  + (size_t)(m0 + rowg) * K + gcol;
    gB[t] = Bt + (size_t)(n0 + rowg) * K + gcol;
    lA[t] = &As[(size_t)(c0 + t) * 512];
    lB[t] = &Bs[(size_t)(c0 + t) * 512];
  }

  f32x4 acc[4][4];
#pragma unroll
  for (int i = 0; i < 4; ++i)
#pragma unroll
    for (int j = 0; j < 4; ++j) acc[i][j] = (f32x4){0.f, 0.f, 0.f, 0.f};

  const int ar  = ln & 15;
  const int hi  = ln >> 4;
  const int arf = (BK == 64) ? (ar & 7) : ((ar >> 1) & 3);

  const int kIters = K / BK;
  for (int kt = 0; kt < kIters; ++kt) {
#pragma unroll
    for (int t = 0; t < LOADS; ++t) gload16(gA[t], lA[t]);
#pragma unroll
    for (int t = 0; t < LOADS; ++t) gload16(gB[t], lB[t]);
#pragma unroll
    for (int t = 0; t < LOADS; ++t) { gA[t] += BK; gB[t] += BK; }
    __syncthreads();

#pragma unroll
    for (int k32 = 0; k32 < BK / 32; ++k32) {
      bf16x8 af[4], bfv[4];
#pragma unroll
      for (int i = 0; i < 4; ++i)
        af[i] = *reinterpret_cast<const bf16x8*>(
            &As[(size_t)(wr * 64 + i * 16 + ar) * BK + (((k32 * 4 + hi) ^ arf) << 3)]);
#pragma unroll
      for (int j = 0; j < 4; ++j)
        bfv[j] = *reinterpret_cast<const bf16x8*>(
            &Bs[(size_t)(wc * 64 + j * 16 + ar) * BK + (((k32 * 4 + hi) ^ arf) << 3)]);
#pragma unroll
      for (int i = 0; i < 4; ++i)
#pragma unroll
        for (int j = 0; j < 4; ++j)
          acc[i][j] = __builtin_amdgcn_mfma_f32_16x16x32_bf16(af[i], bfv[j], acc[i][j], 0, 0, 0);
    }
    __syncthreads();
  }

  const int m0w = m0 + wr * 64 + (ln >> 4) * 4;
  const int n0w = n0 + wc * 64 + (ln & 15);
  u16* outb = (u16*)outp;
#pragma unroll
  for (int j = 0; j < 4; ++j) {
    const int n = n0w + j * 16;
    const float bv = bias[n];
#pragma unroll
    for (int i = 0; i < 4; ++i) {
#pragma unroll
      for (int r = 0; r < 4; ++r) {
        const int m = m0w + i * 16 + r;
        outb[(size_t)m * out_stride + out_col0 + n] = f2bf(eluf(acc[i][j][r] + bv));
      }
    }
  }
}

// ---------------------------------------------------------------------------
// Gating layer 1 GEMM: 64x128 tile (M x N), 4 waves (1M x 4N), BK=64,
// single-buffer 24 KiB, 2 blocks/CU co-resident (512 blocks).
// ---------------------------------------------------------------------------
__global__ __launch_bounds__(256) void gemm_g(
    const u16* __restrict__ A, const u16* __restrict__ Bt,
    const float* __restrict__ bias, void* __restrict__ outp,
    int K, int out_stride, int out_col0) {
  constexpr int BK = 64;
  __shared__ alignas(16) u16 As[64 * BK];    // 8 KiB
  __shared__ alignas(16) u16 Bs[128 * BK];   // 16 KiB

  const int tid = threadIdx.x;
  const int ln  = tid & 63;
  const int wv  = tid >> 6;       // 0..3
  const int wc  = wv;             // N quarter
  const int m0  = blockIdx.y * 64;
  const int n0  = blockIdx.x * 128;

  const int lrow  = ln >> 3;          // 0..7
  const int gslot = (ln & 7) ^ lrow;  // pre-swizzled 16B slot
  const u16* gA[2]; const u16* gB[4];
#pragma unroll
  for (int q = 0; q < 2; ++q)
    gA[q] = A + (size_t)(m0 + (wv * 2 + q) * 8 + lrow) * K + gslot * 8;
#pragma unroll
  for (int q = 0; q < 4; ++q)
    gB[q] = Bt + (size_t)(n0 + (wv * 4 + q) * 8 + lrow) * K + gslot * 8;

  f32x4 acc[4][2];
#pragma unroll
  for (int i = 0; i < 4; ++i)
#pragma unroll
    for (int j = 0; j < 2; ++j) acc[i][j] = (f32x4){0.f, 0.f, 0.f, 0.f};

  const int ar  = ln & 15;
  const int hi  = ln >> 4;
  const int arf = ar & 7;
  const int sl0 = (hi ^ arf) << 3;
  const int sl1 = ((4 + hi) ^ arf) << 3;

  const int nt = K / BK;
  for (int t = 0; t < nt; ++t) {
#pragma unroll
    for (int q = 0; q < 2; ++q) {
      gload16(gA[q], &As[(size_t)((wv * 2 + q) * 8) * 64]);
      gA[q] += BK;
    }
#pragma unroll
    for (int q = 0; q < 4; ++q) {
      gload16(gB[q], &Bs[(size_t)((wv * 4 + q) * 8) * 64]);
      gB[q] += BK;
    }
    __syncthreads();

#pragma unroll
    for (int kk = 0; kk < 2; ++kk) {
      const int sl = kk ? sl1 : sl0;
      bf16x8 av[4], bv[2];
#pragma unroll
      for (int i = 0; i < 4; ++i)
        av[i] = *reinterpret_cast<const bf16x8*>(&As[(size_t)(i * 16 + ar) * 64 + sl]);
#pragma unroll
      for (int j = 0; j < 2; ++j)
        bv[j] = *reinterpret_cast<const bf16x8*>(
            &Bs[(size_t)(wc * 32 + j * 16 + ar) * 64 + sl]);
      __builtin_amdgcn_s_setprio(1);
#pragma unroll
      for (int i = 0; i < 4; ++i)
#pragma unroll
        for (int j = 0; j < 2; ++j)
          acc[i][j] = __builtin_amdgcn_mfma_f32_16x16x32_bf16(av[i], bv[j], acc[i][j], 0, 0, 0);
      __builtin_amdgcn_s_setprio(0);
    }
    __syncthreads();
  }

  u16* outb = (u16*)outp;
#pragma unroll
  for (int j = 0; j < 2; ++j) {
    const int n = n0 + wc * 32 + j * 16 + (ln & 15);
    const float bv = bias[n];
#pragma unroll
    for (int i = 0; i < 4; ++i) {
#pragma unroll
      for (int r = 0; r < 4; ++r) {
        const int m = m0 + i * 16 + hi * 4 + r;
        outb[(size_t)m * out_stride + out_col0 + n] = f2bf(eluf(acc[i][j][r] + bv));
      }
    }
  }
}

// ---------------------------------------------------------------------------
// Expert GEMM (exact R10 kernel, proven 60 us / 0 conflicts): 128x128 tile,
// 4 waves, BK=64, single-buffer 32 KiB, 3 blocks/CU, 16x16x32 MFMA with
// TRANSPOSED output: acc[i][j] = mfma(bv[i], av[j], .) = D[n, m].
//   n = n0 + wc*64 + i*16 + hi*4 + r -> e = (hi&1)*4 + r (register-local),
//   dout = ((n0+wc*64+i*16)>>3) + (hi>>1); m = m0 + wr*64 + j*16 + (ln&15).
// Expert reduction: 4 reg-local FMA + ONE shfl_xor(16).
// MODE 1: bf16 write + elu. MODE 2: fp32 write, no elu (final layer).
// ---------------------------------------------------------------------------
template <int MODE>
__global__ __launch_bounds__(256, 3) void gemm128e(
    const u16* __restrict__ A, const u16* __restrict__ Bt,
    const float* __restrict__ bias, const float* __restrict__ ew,
    void* __restrict__ outp, int N, int K, int out_stride, int out_col0) {
  constexpr int BK = 64;
  __shared__ alignas(16) u16 As[128 * BK];  // 16 KiB
  __shared__ alignas(16) u16 Bs[128 * BK];  // 16 KiB

  const int tid = threadIdx.x;
  const int ln  = tid & 63;
  const int wv  = tid >> 6;       // 0..3
  const int wr  = wv >> 1;        // M half
  const int wc  = wv & 1;         // N half
  const int m0  = blockIdx.y * 128;
  const int n0  = blockIdx.x * 128;

  const int lrow  = ln >> 3;          // 0..7 row within chunk
  const int gslot = (ln & 7) ^ lrow;  // pre-swizzled 16B slot within row
  const u16* gA[4]; const u16* gB[4];
#pragma unroll
  for (int q = 0; q < 4; ++q) {
    const int row = wv * 32 + q * 8 + lrow;
    gA[q] = A  + (size_t)(m0 + row) * K + gslot * 8;
    gB[q] = Bt + (size_t)(n0 + row) * K + gslot * 8;
  }

  f32x4 acc[4][4];
#pragma unroll
  for (int i = 0; i < 4; ++i)
#pragma unroll
    for (int j = 0; j < 4; ++j) acc[i][j] = (f32x4){0.f, 0.f, 0.f, 0.f};

  const int ar  = ln & 15;
  const int hi  = ln >> 4;       // 0..3
  const int arf = ar & 7;        // read-side swizzle
  const int sl0 = (hi ^ arf) << 3;        // kk=0 u16 offset
  const int sl1 = ((4 + hi) ^ arf) << 3;  // kk=1 u16 offset

  const int nt = K / BK;

  for (int t = 0; t < nt; ++t) {
#pragma unroll
    for (int q = 0; q < 4; ++q) {
      gload16(gA[q], &As[(size_t)(wv * 32 + q * 8) * 64]);
      gload16(gB[q], &Bs[(size_t)(wv * 32 + q * 8) * 64]);
      gA[q] += BK; gB[q] += BK;
    }
    __syncthreads();  // drains vmcnt(0): tile staged & visible

    const u16* Ab = &As[(size_t)(wr * 64 + ar) * BK];
    const u16* Bb = &Bs[(size_t)(wc * 64 + ar) * BK];
#pragma unroll
    for (int kk = 0; kk < 2; ++kk) {
      const int sl = kk ? sl1 : sl0;
      bf16x8 av[4], bv[4];
#pragma unroll
      for (int i = 0; i < 4; ++i)
        av[i] = *reinterpret_cast<const bf16x8*>(Ab + (size_t)i * 16 * BK + sl);
#pragma unroll
      for (int j = 0; j < 4; ++j)
        bv[j] = *reinterpret_cast<const bf16x8*>(Bb + (size_t)j * 16 * BK + sl);
      __builtin_amdgcn_s_setprio(1);
#pragma unroll
      for (int i = 0; i < 4; ++i)
#pragma unroll
        for (int j = 0; j < 4; ++j)
          acc[i][j] = __builtin_amdgcn_mfma_f32_16x16x32_bf16(bv[i], av[j], acc[i][j], 0, 0, 0);
      __builtin_amdgcn_s_setprio(0);
    }
    __syncthreads();  // all reads done before next stage overwrites
  }

  // Transposed epilogue. acc[i][j] = D[n, m].
  const int lm = ln & 15;
  const int e0 = (hi & 1) * 4;
  const int dhalf = hi >> 1;
  const int Dout = N >> 3;

  float ewv[4][4];   // [j][r] = ew[m(j), e0+r]
#pragma unroll
  for (int j = 0; j < 4; ++j) {
    const int m = m0 + wr * 64 + j * 16 + lm;
#pragma unroll
    for (int r = 0; r < 4; ++r) ewv[j][r] = ew[(size_t)m * 8 + e0 + r];
  }
  float bs[4][4];    // [i][r] = bias[(e0+r)*Dout + dout(i)]
#pragma unroll
  for (int i = 0; i < 4; ++i) {
    const int di = ((n0 + wc * 64 + i * 16) >> 3) + dhalf;
#pragma unroll
    for (int r = 0; r < 4; ++r) bs[i][r] = bias[(size_t)(e0 + r) * Dout + di];
  }

#pragma unroll
  for (int i = 0; i < 4; ++i) {
    const int di = ((n0 + wc * 64 + i * 16) >> 3) + dhalf;
#pragma unroll
    for (int j = 0; j < 4; ++j) {
      float s = 0.f;
#pragma unroll
      for (int r = 0; r < 4; ++r)
        s += (acc[i][j][r] + bs[i][r]) * ewv[j][r];
      s += __shfl_xor(s, 16);   // combine e0-3 with e4-7 (hi pair)
      if ((hi & 1) == 0) {
        const int m = m0 + wr * 64 + j * 16 + lm;
        if (MODE == 1) {
          ((u16*)outp)[(size_t)m * out_stride + out_col0 + di] = f2bf(eluf(s));
        } else {
          ((float*)outp)[(size_t)m * out_stride + di] = s;
        }
      }
    }
  }
}

// ---------------------------------------------------------------------------
extern "C" void kernel_launch(void* const* d_in, const int* in_sizes, int n_in,
                              void* d_out, int out_size, void* d_ws, size_t ws_size,
                              hipStream_t stream) {
  const float* z   = (const float*)d_in[0];
  const float* p   = (const float*)d_in[1];
  const float* vh  = (const float*)d_in[2];
  const float* xc  = (const float*)d_in[3];
  const float* gw0 = (const float*)d_in[4];
  const float* gb0 = (const float*)d_in[5];
  const float* gw1 = (const float*)d_in[6];
  const float* gb1 = (const float*)d_in[7];
  const float* gw2 = (const float*)d_in[8];
  const float* gb2 = (const float*)d_in[9];
  const float* w0  = (const float*)d_in[10];
  const float* b0  = (const float*)d_in[11];
  const float* w1  = (const float*)d_in[12];
  const float* b1  = (const float*)d_in[13];
  const float* w2  = (const float*)d_in[14];
  const float* b2  = (const float*)d_in[15];
  const float* wo  = (const float*)d_in[16];
  const float* bo  = (const float*)d_in[17];
  float* out = (float*)d_out;

  char* ws = (char*)d_ws;
  size_t off = 0;
  auto alloc = [&](size_t bytes) {
    char* pp = ws + off;
    off += (bytes + 255) & ~(size_t)255;
    return pp;
  };
  u16* gw0t  = (u16*)alloc((size_t)512 * 288 * 2);
  u16* gw1t  = (u16*)alloc((size_t)512 * 768 * 2);
  u16* w0t   = (u16*)alloc((size_t)4096 * 576 * 2);
  u16* w1t   = (u16*)alloc((size_t)4096 * 768 * 2);
  u16* w2t   = (u16*)alloc((size_t)4096 * 768 * 2);
  u16* wot   = (u16*)alloc((size_t)2048 * 768 * 2);
  u16* catP  = (u16*)alloc((size_t)8192 * 288 * 2);
  u16* catE0 = (u16*)alloc((size_t)8192 * 576 * 2);
  u16* cat0  = (u16*)alloc((size_t)8192 * 768 * 2);
  u16* cat1  = (u16*)alloc((size_t)8192 * 768 * 2);
  float* ew  = (float*)alloc((size_t)8192 * 8 * 4);
  (void)ws_size; (void)in_sizes; (void)n_in; (void)out_size;

  transpose_all<<<10512, dim3(32, 8), 0, stream>>>(gw0, gw0t, gw1, gw1t,
                                                   w0, w0t, w1, w1t,
                                                   w2, w2t, wo, wot);
  prep_cat<<<8192, 256, 0, stream>>>(z, p, vh, xc, catP, catE0, cat0, cat1);

  // gating
  gemm_mfma<0, 32><<<dim3(4, 64), 256, 0, stream>>>(catP, gw0t, gb0, nullptr, cat0,
                                                    8192, 512, 288, 768, 256);
  gemm_g<<<dim3(4, 128), 256, 0, stream>>>(cat0, gw1t, gb1, cat1, 768, 768, 256);
  gating_tail<<<2048, 256, 0, stream>>>(cat1, gw2, gb2, ew);

  // expert layers: R10 kernel (16x16x32, transposed epilogue, 3 blocks/CU)
  gemm128e<1><<<dim3(32, 64), 256, 0, stream>>>(catE0, w0t, b0, ew, cat0,
                                                4096, 576, 768, 256);
  gemm128e<1><<<dim3(32, 64), 256, 0, stream>>>(cat0, w1t, b1, ew, cat1,
                                                4096, 768, 768, 256);
  gemm128e<1><<<dim3(32, 64), 256, 0, stream>>>(cat1, w2t, b2, ew, cat0,
                                                4096, 768, 768, 256);
  gemm128e<2><<<dim3(16, 64), 256, 0, stream>>>(cat0, wot, bo, ew, out,
                                                2048, 768, 256, 0);
}

// Round 13
// 263.157 us; speedup vs baseline: 1.1405x; 1.0228x over previous
//
#include <hip/hip_runtime.h>
#include <cstdint>
#include <cstddef>

using u16 = unsigned short;
using bf16x8 = __attribute__((ext_vector_type(8))) __bf16;
using f32x4  = __attribute__((ext_vector_type(4))) float;

static __device__ __forceinline__ u16 f2bf(float f) {
  unsigned u = __builtin_bit_cast(unsigned, f);
  unsigned r = (u + 0x7fffu + ((u >> 16) & 1u)) >> 16;  // RNE
  return (u16)r;
}
static __device__ __forceinline__ float bf2f(u16 h) {
  unsigned u = ((unsigned)h) << 16;
  return __builtin_bit_cast(float, u);
}
static __device__ __forceinline__ float eluf(float x) {
  return x > 0.f ? x : expm1f(x);
}
static __device__ __forceinline__ void gload16(const u16* g, u16* l) {
  __builtin_amdgcn_global_load_lds(
      (const __attribute__((address_space(1))) void*)g,
      (__attribute__((address_space(3))) void*)l, 16, 0, 0);
}

// ---------------------------------------------------------------------------
// Merged weight transpose+convert: all 6 matrices in one launch.
// src (E, Ksrc, Nsrc) f32 -> dst bf16 (Nsrc*E, Kpad), row n' = dout*E + e.
// seg0 (gw0) now pads K 272 -> 320 (gemm_g needs K % 64 == 0).
// ---------------------------------------------------------------------------
__global__ void transpose_all(const float* __restrict__ s0, u16* __restrict__ d0,
                              const float* __restrict__ s1, u16* __restrict__ d1,
                              const float* __restrict__ s2, u16* __restrict__ d2,
                              const float* __restrict__ s3, u16* __restrict__ d3,
                              const float* __restrict__ s4, u16* __restrict__ d4,
                              const float* __restrict__ s5, u16* __restrict__ d5) {
  // seg: blocks = nKb * nDb * E
  // 0 gw0: K272->320, N512, E1 : 10*16    =160   [0,160)
  // 1 gw1: K768,      N512, E1 : 24*16    =384   [160,544)
  // 2 w0 : K515->576, N512, E8 : 18*16*8  =2304  [544,2848)
  // 3 w1 : K768,      N512, E8 : 24*16*8  =3072  [2848,5920)
  // 4 w2 : K768,      N512, E8 : 3072            [5920,8992)
  // 5 wo : K768,      N256, E8 : 24*8*8   =1536  [8992,10528)
  const int bid = blockIdx.x;
  const float* src; u16* dst;
  int Ksrc, Nsrc, Kpad, nKb, local;
  if (bid < 160)       { src=s0; dst=d0; Ksrc=272; Nsrc=512; Kpad=320; nKb=10; local=bid; }
  else if (bid < 544)  { src=s1; dst=d1; Ksrc=768; Nsrc=512; Kpad=768; nKb=24; local=bid-160; }
  else if (bid < 2848) { src=s2; dst=d2; Ksrc=515; Nsrc=512; Kpad=576; nKb=18; local=bid-544; }
  else if (bid < 5920) { src=s3; dst=d3; Ksrc=768; Nsrc=512; Kpad=768; nKb=24; local=bid-2848; }
  else if (bid < 8992) { src=s4; dst=d4; Ksrc=768; Nsrc=512; Kpad=768; nKb=24; local=bid-5920; }
  else                 { src=s5; dst=d5; Ksrc=768; Nsrc=256; Kpad=768; nKb=24; local=bid-8992; }
  const int nDb   = Nsrc >> 5;
  const int perE  = nKb * nDb;
  const int e     = local / perE;
  const int rem   = local - e * perE;
  const int k0    = (rem % nKb) * 32;
  const int d0i   = (rem / nKb) * 32;
  const int E     = (bid < 544) ? 1 : 8;

  __shared__ float tile[32][33];
  const int tx = threadIdx.x;  // 0..31
  const int ty = threadIdx.y;  // 0..7
  const float* s = src + (size_t)e * Ksrc * Nsrc;
#pragma unroll
  for (int i = 0; i < 4; ++i) {
    const int k = k0 + ty + i * 8;
    float v = 0.f;
    if (k < Ksrc) v = s[(size_t)k * Nsrc + d0i + tx];
    tile[ty + i * 8][tx] = v;
  }
  __syncthreads();
#pragma unroll
  for (int i = 0; i < 4; ++i) {
    const int d = d0i + ty + i * 8;
    dst[((size_t)d * E + e) * Kpad + k0 + tx] = f2bf(tile[tx][ty + i * 8]);
  }
}

// ---------------------------------------------------------------------------
// Build bf16 concat buffers.
//   catP  (8192 x 320): [z(256) | p(16) | 0(48)]
//   catE0 (8192 x 576): [z(256) | v(3) | x_curr(256) | 0(61)]
//   cat0, cat1 (8192 x 768): [z(256) | <filled later>]
// ---------------------------------------------------------------------------
__global__ void prep_cat(const float* __restrict__ z, const float* __restrict__ p,
                         const float* __restrict__ vh, const float* __restrict__ xc,
                         u16* __restrict__ catP, u16* __restrict__ catE0,
                         u16* __restrict__ cat0, u16* __restrict__ cat1) {
  const int m = blockIdx.x;
  const int t = threadIdx.x;  // 0..255
  const u16 zb = f2bf(z[(size_t)m * 256 + t]);
  catP [(size_t)m * 320 + t] = zb;
  catE0[(size_t)m * 576 + t] = zb;
  cat0 [(size_t)m * 768 + t] = zb;
  cat1 [(size_t)m * 768 + t] = zb;
  if (t < 64) {
    const u16 val = (t < 16) ? f2bf(p[(size_t)m * 16 + t]) : (u16)0;
    catP[(size_t)m * 320 + 256 + t] = val;
  }
  for (int c = 256 + t; c < 576; c += 256) {
    const int idx = c - 256;
    float v = 0.f;
    if (idx < 3)        v = vh[(size_t)m * 3 + idx];
    else if (idx < 259) v = xc[(size_t)m * 256 + (idx - 3)];
    catE0[(size_t)m * 576 + c] = f2bf(v);
  }
}

// ---------------------------------------------------------------------------
// Gating layer 2 (N=8) + softmax: one wave per token.
// ---------------------------------------------------------------------------
__global__ __launch_bounds__(256) void gating_tail(const u16* __restrict__ cat,
                                                   const float* __restrict__ gw2,
                                                   const float* __restrict__ gb2,
                                                   float* __restrict__ ew) {
  const int ln = threadIdx.x & 63;
  const int token = (int)((blockIdx.x * 256 + threadIdx.x) >> 6);
  const u16* row = cat + (size_t)token * 768;
  float a[8] = {0.f, 0.f, 0.f, 0.f, 0.f, 0.f, 0.f, 0.f};
#pragma unroll
  for (int kk = 0; kk < 12; ++kk) {
    const int k = kk * 64 + ln;
    const float x = bf2f(row[k]);
    const float4* wr = reinterpret_cast<const float4*>(gw2 + (size_t)k * 8);
    const float4 w0 = wr[0], w1 = wr[1];
    a[0] += x * w0.x; a[1] += x * w0.y; a[2] += x * w0.z; a[3] += x * w0.w;
    a[4] += x * w1.x; a[5] += x * w1.y; a[6] += x * w1.z; a[7] += x * w1.w;
  }
#pragma unroll
  for (int j = 0; j < 8; ++j) {
#pragma unroll
    for (int d = 32; d > 0; d >>= 1) a[j] += __shfl_xor(a[j], d);
    a[j] += gb2[j];
  }
  float mx = a[0];
#pragma unroll
  for (int j = 1; j < 8; ++j) mx = fmaxf(mx, a[j]);
  float s = 0.f, pj[8];
#pragma unroll
  for (int j = 0; j < 8; ++j) { pj[j] = expf(a[j] - mx); s += pj[j]; }
  const float inv = 1.f / s;
  if (ln == 0) {
#pragma unroll
    for (int j = 0; j < 8; ++j) ew[(size_t)token * 8 + j] = pj[j] * inv;
  }
}

// ---------------------------------------------------------------------------
// Gating GEMM (layers 0 and 1): 64x128 tile (M x N), 4 waves (1M x 4N),
// BK=64, single-buffer 24 KiB, 2 blocks/CU co-resident (512 blocks).
// bf16 out at [m][out_col0+n], +bias[n], elu.
// ---------------------------------------------------------------------------
__global__ __launch_bounds__(256) void gemm_g(
    const u16* __restrict__ A, const u16* __restrict__ Bt,
    const float* __restrict__ bias, void* __restrict__ outp,
    int K, int out_stride, int out_col0) {
  constexpr int BK = 64;
  __shared__ alignas(16) u16 As[64 * BK];    // 8 KiB
  __shared__ alignas(16) u16 Bs[128 * BK];   // 16 KiB

  const int tid = threadIdx.x;
  const int ln  = tid & 63;
  const int wv  = tid >> 6;       // 0..3
  const int wc  = wv;             // N quarter
  const int m0  = blockIdx.y * 64;
  const int n0  = blockIdx.x * 128;

  const int lrow  = ln >> 3;          // 0..7
  const int gslot = (ln & 7) ^ lrow;  // pre-swizzled 16B slot
  const u16* gA[2]; const u16* gB[4];
#pragma unroll
  for (int q = 0; q < 2; ++q)
    gA[q] = A + (size_t)(m0 + (wv * 2 + q) * 8 + lrow) * K + gslot * 8;
#pragma unroll
  for (int q = 0; q < 4; ++q)
    gB[q] = Bt + (size_t)(n0 + (wv * 4 + q) * 8 + lrow) * K + gslot * 8;

  f32x4 acc[4][2];
#pragma unroll
  for (int i = 0; i < 4; ++i)
#pragma unroll
    for (int j = 0; j < 2; ++j) acc[i][j] = (f32x4){0.f, 0.f, 0.f, 0.f};

  const int ar  = ln & 15;
  const int hi  = ln >> 4;
  const int arf = ar & 7;
  const int sl0 = (hi ^ arf) << 3;
  const int sl1 = ((4 + hi) ^ arf) << 3;

  const int nt = K / BK;
  for (int t = 0; t < nt; ++t) {
#pragma unroll
    for (int q = 0; q < 2; ++q) {
      gload16(gA[q], &As[(size_t)((wv * 2 + q) * 8) * 64]);
      gA[q] += BK;
    }
#pragma unroll
    for (int q = 0; q < 4; ++q) {
      gload16(gB[q], &Bs[(size_t)((wv * 4 + q) * 8) * 64]);
      gB[q] += BK;
    }
    __syncthreads();

#pragma unroll
    for (int kk = 0; kk < 2; ++kk) {
      const int sl = kk ? sl1 : sl0;
      bf16x8 av[4], bv[2];
#pragma unroll
      for (int i = 0; i < 4; ++i)
        av[i] = *reinterpret_cast<const bf16x8*>(&As[(size_t)(i * 16 + ar) * 64 + sl]);
#pragma unroll
      for (int j = 0; j < 2; ++j)
        bv[j] = *reinterpret_cast<const bf16x8*>(
            &Bs[(size_t)(wc * 32 + j * 16 + ar) * 64 + sl]);
      __builtin_amdgcn_s_setprio(1);
#pragma unroll
      for (int i = 0; i < 4; ++i)
#pragma unroll
        for (int j = 0; j < 2; ++j)
          acc[i][j] = __builtin_amdgcn_mfma_f32_16x16x32_bf16(av[i], bv[j], acc[i][j], 0, 0, 0);
      __builtin_amdgcn_s_setprio(0);
    }
    __syncthreads();
  }

  u16* outb = (u16*)outp;
#pragma unroll
  for (int j = 0; j < 2; ++j) {
    const int n = n0 + wc * 32 + j * 16 + (ln & 15);
    const float bv = bias[n];
#pragma unroll
    for (int i = 0; i < 4; ++i) {
#pragma unroll
      for (int r = 0; r < 4; ++r) {
        const int m = m0 + i * 16 + hi * 4 + r;
        outb[(size_t)m * out_stride + out_col0 + n] = f2bf(eluf(acc[i][j][r] + bv));
      }
    }
  }
}

// ---------------------------------------------------------------------------
// Expert GEMM (R10/R12 kernel, proven 60 us / 0 conflicts): 128x128 tile,
// 4 waves, BK=64, single-buffer 32 KiB, 16x16x32 MFMA with TRANSPOSED
// output: acc[i][j] = mfma(bv[i], av[j], .) = D[n, m].
//   n = n0 + wc*64 + i*16 + hi*4 + r -> e = (hi&1)*4 + r (register-local),
//   dout = ((n0+wc*64+i*16)>>3) + (hi>>1); m = m0 + wr*64 + j*16 + (ln&15).
// Expert reduction: 4 reg-local FMA + ONE shfl_xor(16).
// __launch_bounds__(256, 4): reg budget 128 = current exact usage (64 arch
// VGPR + 64 acc AGPR) -> 4 blocks/CU co-resident (was 3). R7 lesson: watch
// for spill (VGPR drop + FETCH explosion) and revert if seen.
// MODE 1: bf16 write + elu. MODE 2: fp32 write, no elu (final layer).
// ---------------------------------------------------------------------------
template <int MODE>
__global__ __launch_bounds__(256, 4) void gemm128e(
    const u16* __restrict__ A, const u16* __restrict__ Bt,
    const float* __restrict__ bias, const float* __restrict__ ew,
    void* __restrict__ outp, int N, int K, int out_stride, int out_col0) {
  constexpr int BK = 64;
  __shared__ alignas(16) u16 As[128 * BK];  // 16 KiB
  __shared__ alignas(16) u16 Bs[128 * BK];  // 16 KiB

  const int tid = threadIdx.x;
  const int ln  = tid & 63;
  const int wv  = tid >> 6;       // 0..3
  const int wr  = wv >> 1;        // M half
  const int wc  = wv & 1;         // N half
  const int m0  = blockIdx.y * 128;
  const int n0  = blockIdx.x * 128;

  const int lrow  = ln >> 3;          // 0..7 row within chunk
  const int gslot = (ln & 7) ^ lrow;  // pre-swizzled 16B slot within row
  const u16* gA[4]; const u16* gB[4];
#pragma unroll
  for (int q = 0; q < 4; ++q) {
    const int row = wv * 32 + q * 8 + lrow;
    gA[q] = A  + (size_t)(m0 + row) * K + gslot * 8;
    gB[q] = Bt + (size_t)(n0 + row) * K + gslot * 8;
  }

  f32x4 acc[4][4];
#pragma unroll
  for (int i = 0; i < 4; ++i)
#pragma unroll
    for (int j = 0; j < 4; ++j) acc[i][j] = (f32x4){0.f, 0.f, 0.f, 0.f};

  const int ar  = ln & 15;
  const int hi  = ln >> 4;       // 0..3
  const int arf = ar & 7;        // read-side swizzle
  const int sl0 = (hi ^ arf) << 3;        // kk=0 u16 offset
  const int sl1 = ((4 + hi) ^ arf) << 3;  // kk=1 u16 offset

  const int nt = K / BK;

  for (int t = 0; t < nt; ++t) {
#pragma unroll
    for (int q = 0; q < 4; ++q) {
      gload16(gA[q], &As[(size_t)(wv * 32 + q * 8) * 64]);
      gload16(gB[q], &Bs[(size_t)(wv * 32 + q * 8) * 64]);
      gA[q] += BK; gB[q] += BK;
    }
    __syncthreads();  // drains vmcnt(0): tile staged & visible

    const u16* Ab = &As[(size_t)(wr * 64 + ar) * BK];
    const u16* Bb = &Bs[(size_t)(wc * 64 + ar) * BK];
#pragma unroll
    for (int kk = 0; kk < 2; ++kk) {
      const int sl = kk ? sl1 : sl0;
      bf16x8 av[4], bv[4];
#pragma unroll
      for (int i = 0; i < 4; ++i)
        av[i] = *reinterpret_cast<const bf16x8*>(Ab + (size_t)i * 16 * BK + sl);
#pragma unroll
      for (int j = 0; j < 4; ++j)
        bv[j] = *reinterpret_cast<const bf16x8*>(Bb + (size_t)j * 16 * BK + sl);
      __builtin_amdgcn_s_setprio(1);
#pragma unroll
      for (int i = 0; i < 4; ++i)
#pragma unroll
        for (int j = 0; j < 4; ++j)
          acc[i][j] = __builtin_amdgcn_mfma_f32_16x16x32_bf16(bv[i], av[j], acc[i][j], 0, 0, 0);
      __builtin_amdgcn_s_setprio(0);
    }
    __syncthreads();  // all reads done before next stage overwrites
  }

  // Transposed epilogue. acc[i][j] = D[n, m].
  const int lm = ln & 15;
  const int e0 = (hi & 1) * 4;
  const int dhalf = hi >> 1;
  const int Dout = N >> 3;

  float ewv[4][4];   // [j][r] = ew[m(j), e0+r]
#pragma unroll
  for (int j = 0; j < 4; ++j) {
    const int m = m0 + wr * 64 + j * 16 + lm;
#pragma unroll
    for (int r = 0; r < 4; ++r) ewv[j][r] = ew[(size_t)m * 8 + e0 + r];
  }
  float bs[4][4];    // [i][r] = bias[(e0+r)*Dout + dout(i)]
#pragma unroll
  for (int i = 0; i < 4; ++i) {
    const int di = ((n0 + wc * 64 + i * 16) >> 3) + dhalf;
#pragma unroll
    for (int r = 0; r < 4; ++r) bs[i][r] = bias[(size_t)(e0 + r) * Dout + di];
  }

#pragma unroll
  for (int i = 0; i < 4; ++i) {
    const int di = ((n0 + wc * 64 + i * 16) >> 3) + dhalf;
#pragma unroll
    for (int j = 0; j < 4; ++j) {
      float s = 0.f;
#pragma unroll
      for (int r = 0; r < 4; ++r)
        s += (acc[i][j][r] + bs[i][r]) * ewv[j][r];
      s += __shfl_xor(s, 16);   // combine e0-3 with e4-7 (hi pair)
      if ((hi & 1) == 0) {
        const int m = m0 + wr * 64 + j * 16 + lm;
        if (MODE == 1) {
          ((u16*)outp)[(size_t)m * out_stride + out_col0 + di] = f2bf(eluf(s));
        } else {
          ((float*)outp)[(size_t)m * out_stride + di] = s;
        }
      }
    }
  }
}

// ---------------------------------------------------------------------------
extern "C" void kernel_launch(void* const* d_in, const int* in_sizes, int n_in,
                              void* d_out, int out_size, void* d_ws, size_t ws_size,
                              hipStream_t stream) {
  const float* z   = (const float*)d_in[0];
  const float* p   = (const float*)d_in[1];
  const float* vh  = (const float*)d_in[2];
  const float* xc  = (const float*)d_in[3];
  const float* gw0 = (const float*)d_in[4];
  const float* gb0 = (const float*)d_in[5];
  const float* gw1 = (const float*)d_in[6];
  const float* gb1 = (const float*)d_in[7];
  const float* gw2 = (const float*)d_in[8];
  const float* gb2 = (const float*)d_in[9];
  const float* w0  = (const float*)d_in[10];
  const float* b0  = (const float*)d_in[11];
  const float* w1  = (const float*)d_in[12];
  const float* b1  = (const float*)d_in[13];
  const float* w2  = (const float*)d_in[14];
  const float* b2  = (const float*)d_in[15];
  const float* wo  = (const float*)d_in[16];
  const float* bo  = (const float*)d_in[17];
  float* out = (float*)d_out;

  char* ws = (char*)d_ws;
  size_t off = 0;
  auto alloc = [&](size_t bytes) {
    char* pp = ws + off;
    off += (bytes + 255) & ~(size_t)255;
    return pp;
  };
  u16* gw0t  = (u16*)alloc((size_t)512 * 320 * 2);
  u16* gw1t  = (u16*)alloc((size_t)512 * 768 * 2);
  u16* w0t   = (u16*)alloc((size_t)4096 * 576 * 2);
  u16* w1t   = (u16*)alloc((size_t)4096 * 768 * 2);
  u16* w2t   = (u16*)alloc((size_t)4096 * 768 * 2);
  u16* wot   = (u16*)alloc((size_t)2048 * 768 * 2);
  u16* catP  = (u16*)alloc((size_t)8192 * 320 * 2);
  u16* catE0 = (u16*)alloc((size_t)8192 * 576 * 2);
  u16* cat0  = (u16*)alloc((size_t)8192 * 768 * 2);
  u16* cat1  = (u16*)alloc((size_t)8192 * 768 * 2);
  float* ew  = (float*)alloc((size_t)8192 * 8 * 4);
  (void)ws_size; (void)in_sizes; (void)n_in; (void)out_size;

  transpose_all<<<10528, dim3(32, 8), 0, stream>>>(gw0, gw0t, gw1, gw1t,
                                                   w0, w0t, w1, w1t,
                                                   w2, w2t, wo, wot);
  prep_cat<<<8192, 256, 0, stream>>>(z, p, vh, xc, catP, catE0, cat0, cat1);

  // gating: both layers on the 2-blocks/CU gemm_g
  gemm_g<<<dim3(4, 128), 256, 0, stream>>>(catP, gw0t, gb0, cat0, 320, 768, 256);
  gemm_g<<<dim3(4, 128), 256, 0, stream>>>(cat0, gw1t, gb1, cat1, 768, 768, 256);
  gating_tail<<<2048, 256, 0, stream>>>(cat1, gw2, gb2, ew);

  // expert layers: R12 kernel at 4 blocks/CU
  gemm128e<1><<<dim3(32, 64), 256, 0, stream>>>(catE0, w0t, b0, ew, cat0,
                                                4096, 576, 768, 256);
  gemm128e<1><<<dim3(32, 64), 256, 0, stream>>>(cat0, w1t, b1, ew, cat1,
                                                4096, 768, 768, 256);
  gemm128e<1><<<dim3(32, 64), 256, 0, stream>>>(cat1, w2t, b2, ew, cat0,
                                                4096, 768, 768, 256);
  gemm128e<2><<<dim3(16, 64), 256, 0, stream>>>(cat0, wot, bo, ew, out,
                                                2048, 768, 256, 0);
}